// Round 7
// baseline (112.388 us; speedup 1.0000x reference)
//
#include <hip/hip_runtime.h>

typedef __attribute__((ext_vector_type(8))) short short8;
typedef __attribute__((ext_vector_type(4))) short short4v;
typedef __attribute__((ext_vector_type(4))) float f32x4;
typedef __attribute__((ext_vector_type(4))) int i32x4;

#define NN 8192
#define ALPHA 0.2f

__device__ __forceinline__ float bf16_to_f32(unsigned short h) {
    union { unsigned int u; float f; } c;
    c.u = ((unsigned int)h) << 16;
    return c.f;
}
__device__ __forceinline__ unsigned short f32_to_bf16(float f) {
    union { float f; unsigned int u; } c;
    c.f = f;
    unsigned int r = (c.u + 0x7FFFu + ((c.u >> 16) & 1u)) >> 16;
    return (unsigned short)r;
}
// cheaper round-half-up (pv inner loop only; half-ulp bias, cancels in ratio)
__device__ __forceinline__ unsigned short f32_to_bf16_fast(float f) {
    union { float f; unsigned int u; } c;
    c.f = f;
    return (unsigned short)((c.u + 0x8000u) >> 16);
}

// ---------------- kernel 0: probe input dtype -------------------------------
__global__ void gat_probe_dtype(const unsigned short* __restrict__ x16, int* flag) {
    __shared__ int cnts[256];
    int tid = threadIdx.x;
    int cnt = 0;
    for (int i = tid; i < 16384; i += 256) {
        float v = bf16_to_f32(x16[i]);
        float a = fabsf(v);
        if (a > 1e-6f && a < 64.0f) cnt++;   // false for NaN too
    }
    cnts[tid] = cnt;
    __syncthreads();
    for (int s = 128; s > 0; s >>= 1) {
        if (tid < s) cnts[tid] += cnts[tid + s];
        __syncthreads();
    }
    if (tid == 0) *flag = (cnts[0] > 13000) ? 1 : 0;
}

// ---------------- kernel 1: prep = A-compress (blocks 0..2047) +
//                            input convert (blocks 2048..2303) ---------------
// Compress: wave-per-row; lane l reads A[row][kb + j*64 + l] (256B coalesced
// per load), 4 ballots per 256 ints -> bits[row][128] u64 words, LSB = k%64.
__global__ __launch_bounds__(256) void gat_prep(
    const void* __restrict__ Xv, const void* __restrict__ Wv,
    const void* __restrict__ bv, const void* __restrict__ asv,
    const void* __restrict__ arv, const int* __restrict__ Ain,
    short* __restrict__ Xb, short* __restrict__ Wb,
    float* __restrict__ bF, float* __restrict__ asF, float* __restrict__ arF,
    unsigned long long* __restrict__ bitsW, const int* __restrict__ flag) {
    const int bid = blockIdx.x;
    const int tid = threadIdx.x;
    if (bid < 2048) {
        const int wave = tid >> 6, lane = tid & 63;
        const int row = bid * 4 + wave;
        const int* arow = Ain + (size_t)row * NN;
        unsigned long long* brow = bitsW + (size_t)row * 128;
        for (int step = 0; step < 32; step++) {
            const int kb = step * 256;
            int v0 = arow[kb + lane];
            int v1 = arow[kb + 64 + lane];
            int v2 = arow[kb + 128 + lane];
            int v3 = arow[kb + 192 + lane];
            unsigned long long b0 = __ballot(v0 != 0);
            unsigned long long b1 = __ballot(v1 != 0);
            unsigned long long b2 = __ballot(v2 != 0);
            unsigned long long b3 = __ballot(v3 != 0);
            if (lane < 4) {
                unsigned long long w = (lane == 0) ? b0 : (lane == 1) ? b1
                                     : (lane == 2) ? b2 : b3;
                brow[step * 4 + lane] = w;
            }
        }
        return;
    }
    // ---- convert part (virtual grid of 256 blocks) ----
    const int GX = NN * 256 / 8;
    const int GW = 256 * 256 / 8;
    const int isBf = *flag;
    const int idx = (bid - 2048) * blockDim.x + tid;
    const int stride = 256 * 256;
    for (int i = idx; i < GX + GW; i += stride) {
        const void* src = (i < GX) ? Xv : Wv;
        short* dst = (i < GX) ? Xb : Wb;
        int g = (i < GX) ? i : i - GX;
        short8 o;
        if (isBf) {
            o = ((const short8*)src)[g];
        } else {
            f32x4 a = ((const f32x4*)src)[2 * g];
            f32x4 b = ((const f32x4*)src)[2 * g + 1];
#pragma unroll
            for (int j = 0; j < 4; j++) {
                o[j] = (short)f32_to_bf16(a[j]);
                o[4 + j] = (short)f32_to_bf16(b[j]);
            }
        }
        ((short8*)dst)[g] = o;
    }
    if (idx < 768) {
        int which = idx >> 8;
        int k = idx & 255;
        const void* src = (which == 0) ? bv : (which == 1) ? asv : arv;
        float v = isBf ? bf16_to_f32(((const unsigned short*)src)[k])
                       : ((const float*)src)[k];
        float* dst = (which == 0) ? bF : (which == 1) ? asF : arF;
        dst[k] = v;
    }
}

// ---------------- kernel 2: H_in = X*W^T + b -> Gfrag, s, r ------------------
// Head-summed G emitted in MFMA-B-FRAGMENT-MAJOR order: Gfrag[fid][lane][j],
// fid = ktile*8 + half*4 + n; PV B-loads are 1KB contiguous per instruction.
__global__ __launch_bounds__(128) void gat_gemm1(
    const short* __restrict__ Xb, const short* __restrict__ Wb,
    const float* __restrict__ bF, const float* __restrict__ asF,
    const float* __restrict__ arF,
    short* __restrict__ Gfrag, float* __restrict__ sOut, float* __restrict__ rOut) {
    __shared__ short Gl[64][32];      // [col][local node-row]
    const int tid = threadIdx.x;
    const int wave = tid >> 6, lane = tid & 63;
    const int l15 = lane & 15, lhi = lane >> 4;
    const int rowBase = blockIdx.x * 32 + wave * 16;

    f32x4 acc[16];
#pragma unroll
    for (int n = 0; n < 16; n++) acc[n] = (f32x4){0.f, 0.f, 0.f, 0.f};

    const short8* Xrow = (const short8*)(Xb + (size_t)(rowBase + l15) * 256);
#pragma unroll
    for (int ks = 0; ks < 8; ks++) {            // K = 256 in steps of 32
        short8 a = Xrow[ks * 4 + lhi];
#pragma unroll
        for (int n = 0; n < 16; n++) {
            const short8* Wrow = (const short8*)(Wb + (size_t)(n * 16 + l15) * 256);
            short8 bf = Wrow[ks * 4 + lhi];
            acc[n] = __builtin_amdgcn_mfma_f32_16x16x32_bf16(a, bf, acc[n], 0, 0, 0);
        }
    }

    float sPart[4] = {0.f, 0.f, 0.f, 0.f};
    float rPart[4] = {0.f, 0.f, 0.f, 0.f};
    float g[4][4];
#pragma unroll
    for (int na = 0; na < 4; na++)
#pragma unroll
        for (int q = 0; q < 4; q++) g[na][q] = 0.f;

#pragma unroll
    for (int n = 0; n < 16; n++) {
        int col = n * 16 + l15;
        float bias = bF[col], asc = asF[col], arc = arF[col];
#pragma unroll
        for (int q = 0; q < 4; q++) {
            float h = acc[n][q] + bias;         // D: row=lhi*4+q, col=l15
            sPart[q] += h * asc;
            rPart[q] += h * arc;
            g[n & 3][q] += h;                   // head-sum
        }
    }

    // stage G tile in LDS: Gl[col][klocal], klocal = wave*16 + lhi*4 + q
#pragma unroll
    for (int na = 0; na < 4; na++)
#pragma unroll
        for (int q = 0; q < 4; q++)
            Gl[na * 16 + l15][wave * 16 + lhi * 4 + q] = (short)f32_to_bf16(g[na][q]);

#pragma unroll
    for (int m = 1; m <= 8; m <<= 1) {
#pragma unroll
        for (int q = 0; q < 4; q++) {
            sPart[q] += __shfl_xor(sPart[q], m, 64);
            rPart[q] += __shfl_xor(rPart[q], m, 64);
        }
    }
    if (l15 == 0) {
#pragma unroll
        for (int q = 0; q < 4; q++) {
            int row = rowBase + lhi * 4 + q;
            sOut[row] = sPart[q];
            rOut[row] = rPart[q];
        }
    }

    __syncthreads();
    const int t_ = blockIdx.x >> 1, h_ = blockIdx.x & 1;
#pragma unroll
    for (int e = tid; e < 256; e += 128) {
        int n_ = e >> 6, le = e & 63;
        short8 v = *(const short8*)(&Gl[n_ * 16 + (le & 15)][(le >> 4) * 8]);
        *(short8*)(Gfrag + ((size_t)t_ * 8 + h_ * 4 + n_) * 512 + le * 8) = v;
    }
}

// ---------------- kernel 3: fused masked-softmax PV (v7, bit-mask) ----------
// pv6 structure (1024 blocks = 256 row-blocks x 4 k-slices; wave covers all
// 32 rows, 8 tiles), but the mask comes from the compressed bits buffer:
// each fragment lane loads its own u64 (word = ktile) per row-group - no
// ballots, no cross-lane, A-int stream gone. bits are L2/L3-resident (8MB).

#define GAT_ELEM(PA_, JP_, XV_, TW_, SH_)                                    \
    {                                                                        \
        float x_ = (XV_);                                                    \
        x_ = fmaxf(x_, ALPHA * x_);                                          \
        float e_ = __expf(x_);                                               \
        PA_[JP_] = ((TW_ >> (SH_)) & 1u) ? (short)f32_to_bf16_fast(e_)       \
                                         : (short)0;                         \
    }

#define GAT_PA(PAH0, PAH1, SM_, T0_, T1_)                                    \
    {                                                                        \
        GAT_ELEM(PAH0, 0, (SM_) + ra0[0], T0_, 0)                            \
        GAT_ELEM(PAH0, 1, (SM_) + ra0[1], T0_, 1)                            \
        GAT_ELEM(PAH0, 2, (SM_) + ra0[2], T0_, 2)                            \
        GAT_ELEM(PAH0, 3, (SM_) + ra0[3], T0_, 3)                            \
        GAT_ELEM(PAH0, 4, (SM_) + ra1[0], T0_, 4)                            \
        GAT_ELEM(PAH0, 5, (SM_) + ra1[1], T0_, 5)                            \
        GAT_ELEM(PAH0, 6, (SM_) + ra1[2], T0_, 6)                            \
        GAT_ELEM(PAH0, 7, (SM_) + ra1[3], T0_, 7)                            \
        GAT_ELEM(PAH1, 0, (SM_) + rb0[0], T1_, 0)                            \
        GAT_ELEM(PAH1, 1, (SM_) + rb0[1], T1_, 1)                            \
        GAT_ELEM(PAH1, 2, (SM_) + rb0[2], T1_, 2)                            \
        GAT_ELEM(PAH1, 3, (SM_) + rb0[3], T1_, 3)                            \
        GAT_ELEM(PAH1, 4, (SM_) + rb1[0], T1_, 4)                            \
        GAT_ELEM(PAH1, 5, (SM_) + rb1[1], T1_, 5)                            \
        GAT_ELEM(PAH1, 6, (SM_) + rb1[2], T1_, 6)                            \
        GAT_ELEM(PAH1, 7, (SM_) + rb1[3], T1_, 7)                            \
    }

#define GAT_MFMA_HALF(H_)                                                    \
    {                                                                        \
        const short* bp_ = Gfrag + ((size_t)ktg * 8 + (H_) * 4) * 512 +      \
                           lane * 8;                                         \
        short8 bv0 = *(const short8*)(bp_);                                  \
        short8 bv1 = *(const short8*)(bp_ + 512);                            \
        short8 bv2 = *(const short8*)(bp_ + 1024);                           \
        short8 bv3 = *(const short8*)(bp_ + 1536);                           \
        acc[0][0] = __builtin_amdgcn_mfma_f32_16x16x32_bf16(pa0[H_], bv0,    \
                                                            acc[0][0], 0, 0, 0); \
        acc[0][1] = __builtin_amdgcn_mfma_f32_16x16x32_bf16(pa0[H_], bv1,    \
                                                            acc[0][1], 0, 0, 0); \
        acc[0][2] = __builtin_amdgcn_mfma_f32_16x16x32_bf16(pa0[H_], bv2,    \
                                                            acc[0][2], 0, 0, 0); \
        acc[0][3] = __builtin_amdgcn_mfma_f32_16x16x32_bf16(pa0[H_], bv3,    \
                                                            acc[0][3], 0, 0, 0); \
        acc[0][4] = __builtin_amdgcn_mfma_f32_16x16x32_bf16(pa0[H_], onesB,  \
                                                            acc[0][4], 0, 0, 0); \
        acc[1][0] = __builtin_amdgcn_mfma_f32_16x16x32_bf16(pa1[H_], bv0,    \
                                                            acc[1][0], 0, 0, 0); \
        acc[1][1] = __builtin_amdgcn_mfma_f32_16x16x32_bf16(pa1[H_], bv1,    \
                                                            acc[1][1], 0, 0, 0); \
        acc[1][2] = __builtin_amdgcn_mfma_f32_16x16x32_bf16(pa1[H_], bv2,    \
                                                            acc[1][2], 0, 0, 0); \
        acc[1][3] = __builtin_amdgcn_mfma_f32_16x16x32_bf16(pa1[H_], bv3,    \
                                                            acc[1][3], 0, 0, 0); \
        acc[1][4] = __builtin_amdgcn_mfma_f32_16x16x32_bf16(pa1[H_], onesB,  \
                                                            acc[1][4], 0, 0, 0); \
    }

__global__ __launch_bounds__(256, 3) void gat_pv7(
    const unsigned long long* __restrict__ bitsW, const short* __restrict__ Gfrag,
    const float* __restrict__ sV, const float* __restrict__ rV,
    float* __restrict__ accP, float* __restrict__ denP) {
    __shared__ float Ls[4][32][68];
    __shared__ float Ld[4][32];

    const int tid = threadIdx.x;
    const int wave = tid >> 6, lane = tid & 63;
    const int l15 = lane & 15, lhi = lane >> 4;
    const int rb = blockIdx.x >> 2;
    const int ks = blockIdx.x & 3;
    const int i0 = rb * 32;
    const int ksBase = ks * 32 + wave * 8;      // first 64-k tile (global idx)

    const float s0m = sV[i0 + l15];
    const float s1m = sV[i0 + 16 + l15];
    const unsigned long long* bb0 = bitsW + (size_t)(i0 + l15) * 128;
    const unsigned long long* bb1 = bitsW + (size_t)(i0 + 16 + l15) * 128;
    const float* rvb = rV + lhi * 8;
    const int sh0 = lhi * 8, sh1 = 32 + lhi * 8;

    short8 onesB;
#pragma unroll
    for (int j = 0; j < 8; j++) onesB[j] = (l15 == 0) ? (short)0x3F80 : (short)0;

    f32x4 acc[2][5];
#pragma unroll
    for (int rg = 0; rg < 2; rg++)
#pragma unroll
        for (int n = 0; n < 5; n++) acc[rg][n] = (f32x4){0.f, 0.f, 0.f, 0.f};

    unsigned long long w0 = bb0[ksBase];
    unsigned long long w1 = bb1[ksBase];

    for (int t = 0; t < 8; t++) {
        const int ktg = ksBase + t;
        const int k0 = ktg * 64;
        f32x4 ra0 = *(const f32x4*)(rvb + k0);
        f32x4 ra1 = *(const f32x4*)(rvb + k0 + 4);
        f32x4 rb0 = *(const f32x4*)(rvb + k0 + 32);
        f32x4 rb1 = *(const f32x4*)(rvb + k0 + 36);

        const int tn = (t < 7) ? ktg + 1 : ktg;   // tail: redundant reload
        unsigned long long nw0 = bb0[tn];
        unsigned long long nw1 = bb1[tn];

        const unsigned int t00 = (unsigned int)(w0 >> sh0);
        const unsigned int t01 = (unsigned int)(w0 >> sh1);
        const unsigned int t10 = (unsigned int)(w1 >> sh0);
        const unsigned int t11 = (unsigned int)(w1 >> sh1);

        short8 pa0[2], pa1[2];
        GAT_PA(pa0[0], pa0[1], s0m, t00, t01);
        GAT_PA(pa1[0], pa1[1], s1m, t10, t11);

        GAT_MFMA_HALF(0);
        GAT_MFMA_HALF(1);

        w0 = nw0; w1 = nw1;
    }

    // combine the 4 waves' partials in LDS (single barrier, no atomics)
#pragma unroll
    for (int rg = 0; rg < 2; rg++)
#pragma unroll
        for (int n = 0; n < 4; n++)
#pragma unroll
            for (int q = 0; q < 4; q++)
                Ls[wave][rg * 16 + lhi * 4 + q][n * 16 + l15] = acc[rg][n][q];
    if (l15 == 0) {
#pragma unroll
        for (int rg = 0; rg < 2; rg++)
#pragma unroll
            for (int q = 0; q < 4; q++)
                Ld[wave][rg * 16 + lhi * 4 + q] = acc[rg][4][q];
    }
    __syncthreads();

    const int row = tid >> 3, c0 = (tid & 7) * 8;
    float v[8];
#pragma unroll
    for (int j = 0; j < 8; j++)
        v[j] = Ls[0][row][c0 + j] + Ls[1][row][c0 + j] +
               Ls[2][row][c0 + j] + Ls[3][row][c0 + j];
    float* aout = accP + (size_t)ks * NN * 64 + (size_t)(i0 + row) * 64 + c0;
    *(f32x4*)aout = (f32x4){v[0], v[1], v[2], v[3]};
    *((f32x4*)aout + 1) = (f32x4){v[4], v[5], v[6], v[7]};
    if (tid < 32)
        denP[(size_t)ks * NN + i0 + tid] =
            Ld[0][tid] + Ld[1][tid] + Ld[2][tid] + Ld[3][tid];
}

// ---------------- kernel 4: sum 4 partials, divide, cast --------------------
__global__ void gat_final(const float* __restrict__ accP, const float* __restrict__ denP,
                          const int* __restrict__ flag, void* __restrict__ outP) {
    int idx = blockIdx.x * blockDim.x + threadIdx.x;  // one f32x4 group
    if (idx >= NN * 16) return;
    int row = idx >> 4;
    float den = 0.f;
    f32x4 v = (f32x4){0.f, 0.f, 0.f, 0.f};
#pragma unroll
    for (int sk = 0; sk < 4; sk++) {
        den += denP[(size_t)sk * NN + row];
        f32x4 a = *((const f32x4*)(accP + (size_t)sk * NN * 64) + idx);
        v.x += a.x; v.y += a.y; v.z += a.z; v.w += a.w;
    }
    float inv = 1.0f / den;
    v.x *= inv; v.y *= inv; v.z *= inv; v.w *= inv;
    if (*flag) {
        short4v pk;
#pragma unroll
        for (int j = 0; j < 4; j++) pk[j] = (short)f32_to_bf16(v[j]);
        *((short4v*)outP + idx) = pk;
    } else {
        *((f32x4*)outP + idx) = v;
    }
}

// ---------------- launch -----------------------------------------------------
extern "C" void kernel_launch(void* const* d_in, const int* in_sizes, int n_in,
                              void* d_out, int out_size, void* d_ws, size_t ws_size,
                              hipStream_t stream) {
    const void* X  = d_in[0];
    const int*  A  = (const int*)d_in[1];
    const void* W  = d_in[2];
    const void* bb = d_in[3];
    const void* as_ = d_in[4];
    const void* ar_ = d_in[5];

    char* ws = (char*)d_ws;
    const size_t OFF_FLAG = 0;
    const size_t OFF_XB   = 256;
    const size_t OFF_WB   = OFF_XB + (size_t)NN * 256 * 2;
    const size_t OFF_BF   = OFF_WB + (size_t)256 * 256 * 2;
    const size_t OFF_ASF  = OFF_BF + 1024;
    const size_t OFF_ARF  = OFF_ASF + 1024;
    const size_t OFF_S    = OFF_ARF + 1024;
    const size_t OFF_R    = OFF_S + (size_t)NN * 4;
    const size_t OFF_GF   = OFF_R + (size_t)NN * 4;           // Gfrag, 1 MB
    const size_t OFF_ACC  = OFF_GF + (size_t)64 * NN * 2;
    const size_t OFF_DEN  = OFF_ACC + (size_t)4 * NN * 64 * 4;
    const size_t OFF_BITS = OFF_DEN + (size_t)4 * NN * 4;     // 8 MB

    int*   flag = (int*)(ws + OFF_FLAG);
    short* Xb   = (short*)(ws + OFF_XB);
    short* Wb   = (short*)(ws + OFF_WB);
    float* bF   = (float*)(ws + OFF_BF);
    float* asF  = (float*)(ws + OFF_ASF);
    float* arF  = (float*)(ws + OFF_ARF);
    float* sP   = (float*)(ws + OFF_S);
    float* rP   = (float*)(ws + OFF_R);
    short* Gf   = (short*)(ws + OFF_GF);
    float* accP = (float*)(ws + OFF_ACC);
    float* denP = (float*)(ws + OFF_DEN);
    unsigned long long* bitsW = (unsigned long long*)(ws + OFF_BITS);

    gat_probe_dtype<<<1, 256, 0, stream>>>((const unsigned short*)X, flag);
    gat_prep<<<2304, 256, 0, stream>>>(X, W, bb, as_, ar_, A,
                                       Xb, Wb, bF, asF, arF, bitsW, flag);
    gat_gemm1<<<NN / 32, 128, 0, stream>>>(Xb, Wb, bF, asF, arF, Gf, sP, rP);
    gat_pv7<<<(NN / 32) * 4, 256, 0, stream>>>(bitsW, Gf, sP, rP, accP, denP);
    gat_final<<<NN * 16 / 256, 256, 0, stream>>>(accP, denP, flag, d_out);
}

// Round 8
// 79.747 us; speedup vs baseline: 1.4093x; 1.4093x over previous
//
#include <hip/hip_runtime.h>

typedef __attribute__((ext_vector_type(8))) short short8;
typedef __attribute__((ext_vector_type(4))) short short4v;
typedef __attribute__((ext_vector_type(4))) float f32x4;
typedef __attribute__((ext_vector_type(4))) int i32x4;

#define NN 8192
#define ALPHA 0.2f

__device__ __forceinline__ float bf16_to_f32(unsigned short h) {
    union { unsigned int u; float f; } c;
    c.u = ((unsigned int)h) << 16;
    return c.f;
}
__device__ __forceinline__ unsigned short f32_to_bf16(float f) {
    union { float f; unsigned int u; } c;
    c.f = f;
    unsigned int r = (c.u + 0x7FFFu + ((c.u >> 16) & 1u)) >> 16;
    return (unsigned short)r;
}
// cheaper round-half-up (pv inner loop only; half-ulp bias, cancels in ratio)
__device__ __forceinline__ unsigned short f32_to_bf16_fast(float f) {
    union { float f; unsigned int u; } c;
    c.f = f;
    return (unsigned short)((c.u + 0x8000u) >> 16);
}

// mini-probe: first 1024 halves of X interpreted as bf16. bf16 data -> ~1013
// sane values; f32 data -> ~560 (high halves pass, low halves ~10%).
// Deterministic and identical across blocks.
__device__ __forceinline__ int probe_isbf16(const void* Xv, int tid) {
    __shared__ int wsum[4];
    const unsigned short* x16 = (const unsigned short*)Xv;
    int cnt = 0;
#pragma unroll
    for (int j = 0; j < 4; j++) {
        float v = bf16_to_f32(x16[tid * 4 + j]);
        float a = fabsf(v);
        if (a > 1e-6f && a < 64.0f) cnt++;
    }
#pragma unroll
    for (int m = 1; m <= 32; m <<= 1) cnt += __shfl_xor(cnt, m, 64);
    if ((tid & 63) == 0) wsum[tid >> 6] = cnt;
    __syncthreads();
    return (wsum[0] + wsum[1] + wsum[2] + wsum[3]) > 800;
}

// ---------------- kernel 1: prep = probe + convert (256 blocks) -------------
__global__ __launch_bounds__(256) void gat_prep(
    const void* __restrict__ Xv, const void* __restrict__ Wv,
    const void* __restrict__ bv, const void* __restrict__ asv,
    const void* __restrict__ arv,
    short* __restrict__ Xb, short* __restrict__ Wb,
    float* __restrict__ bF, float* __restrict__ asF, float* __restrict__ arF,
    int* __restrict__ flagOut) {
    const int tid = threadIdx.x;
    const int isBf = probe_isbf16(Xv, tid);
    if (blockIdx.x == 0 && tid == 0) *flagOut = isBf;

    const int GX = NN * 256 / 8;      // short8 groups in X
    const int GW = 256 * 256 / 8;     // short8 groups in W
    const int idx = blockIdx.x * 256 + tid;
    const int stride = 256 * 256;
    for (int i = idx; i < GX + GW; i += stride) {
        const void* src = (i < GX) ? Xv : Wv;
        short* dst = (i < GX) ? Xb : Wb;
        int g = (i < GX) ? i : i - GX;
        short8 o;
        if (isBf) {
            o = ((const short8*)src)[g];
        } else {
            f32x4 a = ((const f32x4*)src)[2 * g];
            f32x4 b = ((const f32x4*)src)[2 * g + 1];
#pragma unroll
            for (int j = 0; j < 4; j++) {
                o[j] = (short)f32_to_bf16(a[j]);
                o[4 + j] = (short)f32_to_bf16(b[j]);
            }
        }
        ((short8*)dst)[g] = o;
    }
    if (idx < 768) {
        int which = idx >> 8;
        int k = idx & 255;
        const void* src = (which == 0) ? bv : (which == 1) ? asv : arv;
        float v = isBf ? bf16_to_f32(((const unsigned short*)src)[k])
                       : ((const float*)src)[k];
        float* dst = (which == 0) ? bF : (which == 1) ? asF : arF;
        dst[k] = v;
    }
}

// ---------------- kernel 2: H_in = X*W^T + b -> Gfrag, s, r ------------------
// Head-summed G emitted in MFMA-B-FRAGMENT-MAJOR order: Gfrag[fid][lane][j],
// fid = ktile*8 + half*4 + n; PV B-loads are 1KB contiguous per instruction.
__global__ __launch_bounds__(128) void gat_gemm1(
    const short* __restrict__ Xb, const short* __restrict__ Wb,
    const float* __restrict__ bF, const float* __restrict__ asF,
    const float* __restrict__ arF,
    short* __restrict__ Gfrag, float* __restrict__ sOut, float* __restrict__ rOut) {
    __shared__ short Gl[64][32];      // [col][local node-row]
    const int tid = threadIdx.x;
    const int wave = tid >> 6, lane = tid & 63;
    const int l15 = lane & 15, lhi = lane >> 4;
    const int rowBase = blockIdx.x * 32 + wave * 16;

    f32x4 acc[16];
#pragma unroll
    for (int n = 0; n < 16; n++) acc[n] = (f32x4){0.f, 0.f, 0.f, 0.f};

    const short8* Xrow = (const short8*)(Xb + (size_t)(rowBase + l15) * 256);
#pragma unroll
    for (int ks = 0; ks < 8; ks++) {            // K = 256 in steps of 32
        short8 a = Xrow[ks * 4 + lhi];
#pragma unroll
        for (int n = 0; n < 16; n++) {
            const short8* Wrow = (const short8*)(Wb + (size_t)(n * 16 + l15) * 256);
            short8 bf = Wrow[ks * 4 + lhi];
            acc[n] = __builtin_amdgcn_mfma_f32_16x16x32_bf16(a, bf, acc[n], 0, 0, 0);
        }
    }

    float sPart[4] = {0.f, 0.f, 0.f, 0.f};
    float rPart[4] = {0.f, 0.f, 0.f, 0.f};
    float g[4][4];
#pragma unroll
    for (int na = 0; na < 4; na++)
#pragma unroll
        for (int q = 0; q < 4; q++) g[na][q] = 0.f;

#pragma unroll
    for (int n = 0; n < 16; n++) {
        int col = n * 16 + l15;
        float bias = bF[col], asc = asF[col], arc = arF[col];
#pragma unroll
        for (int q = 0; q < 4; q++) {
            float h = acc[n][q] + bias;         // D: row=lhi*4+q, col=l15
            sPart[q] += h * asc;
            rPart[q] += h * arc;
            g[n & 3][q] += h;                   // head-sum
        }
    }

    // stage G tile in LDS: Gl[col][klocal], klocal = wave*16 + lhi*4 + q
#pragma unroll
    for (int na = 0; na < 4; na++)
#pragma unroll
        for (int q = 0; q < 4; q++)
            Gl[na * 16 + l15][wave * 16 + lhi * 4 + q] = (short)f32_to_bf16(g[na][q]);

#pragma unroll
    for (int m = 1; m <= 8; m <<= 1) {
#pragma unroll
        for (int q = 0; q < 4; q++) {
            sPart[q] += __shfl_xor(sPart[q], m, 64);
            rPart[q] += __shfl_xor(rPart[q], m, 64);
        }
    }
    if (l15 == 0) {
#pragma unroll
        for (int q = 0; q < 4; q++) {
            int row = rowBase + lhi * 4 + q;
            sOut[row] = sPart[q];
            rOut[row] = rPart[q];
        }
    }

    __syncthreads();
    const int t_ = blockIdx.x >> 1, h_ = blockIdx.x & 1;
#pragma unroll
    for (int e = tid; e < 256; e += 128) {
        int n_ = e >> 6, le = e & 63;
        short8 v = *(const short8*)(&Gl[n_ * 16 + (le & 15)][(le >> 4) * 8]);
        *(short8*)(Gfrag + ((size_t)t_ * 8 + h_ * 4 + n_) * 512 + le * 8) = v;
    }
}

// ---------------- kernel 3: fused masked-softmax PV (v8) --------------------
// pv6 structure with: temporal A loads (L3-warm across replays), grid 768 =
// 256 row-blocks x 3 k-slices (43/43/42 tiles) -> exactly 3 blocks/CU, no
// tail. Wave covers all 32 rows, strided tiles within its slice.

#define GAT_LOADA(S0, S1, S2, S3, AB_, T_)                                   \
    {                                                                        \
        const int* p_ = (AB_) + (size_t)(T_) * 64;                           \
        S0 = *(const i32x4*)(p_);                                            \
        S1 = *(const i32x4*)(p_ + NN);                                       \
        S2 = *(const i32x4*)(p_ + 2 * NN);                                   \
        S3 = *(const i32x4*)(p_ + 3 * NN);                                   \
    }

#define GAT_BAL(Q0, Q1, Q2, Q3, V0, V1, V2, V3)                              \
    {                                                                        \
        unsigned long long W00 = __ballot((V0)[0] != 0);                     \
        unsigned long long W01 = __ballot((V0)[1] != 0);                     \
        unsigned long long W02 = __ballot((V0)[2] != 0);                     \
        unsigned long long W03 = __ballot((V0)[3] != 0);                     \
        unsigned long long W10 = __ballot((V1)[0] != 0);                     \
        unsigned long long W11 = __ballot((V1)[1] != 0);                     \
        unsigned long long W12 = __ballot((V1)[2] != 0);                     \
        unsigned long long W13 = __ballot((V1)[3] != 0);                     \
        unsigned long long W20 = __ballot((V2)[0] != 0);                     \
        unsigned long long W21 = __ballot((V2)[1] != 0);                     \
        unsigned long long W22 = __ballot((V2)[2] != 0);                     \
        unsigned long long W23 = __ballot((V2)[3] != 0);                     \
        unsigned long long W30 = __ballot((V3)[0] != 0);                     \
        unsigned long long W31 = __ballot((V3)[1] != 0);                     \
        unsigned long long W32 = __ballot((V3)[2] != 0);                     \
        unsigned long long W33 = __ballot((V3)[3] != 0);                     \
        unsigned long long w0_ = r3 == 0 ? W00 : r3 == 1 ? W10               \
                               : r3 == 2 ? W20 : W30;                        \
        unsigned long long w1_ = r3 == 0 ? W01 : r3 == 1 ? W11               \
                               : r3 == 2 ? W21 : W31;                        \
        unsigned long long w2_ = r3 == 0 ? W02 : r3 == 1 ? W12               \
                               : r3 == 2 ? W22 : W32;                        \
        unsigned long long w3_ = r3 == 0 ? W03 : r3 == 1 ? W13               \
                               : r3 == 2 ? W23 : W33;                        \
        Q0 = (unsigned int)(w0_ >> shBase);                                  \
        Q1 = (unsigned int)(w1_ >> shBase);                                  \
        Q2 = (unsigned int)(w2_ >> shBase);                                  \
        Q3 = (unsigned int)(w3_ >> shBase);                                  \
    }

#define GAT_ELEM(PA_, JP_, XV_, TW_, SH_)                                    \
    {                                                                        \
        float x_ = (XV_);                                                    \
        x_ = fmaxf(x_, ALPHA * x_);                                          \
        float e_ = __expf(x_);                                               \
        PA_[JP_] = ((TW_ >> (SH_)) & 1u) ? (short)f32_to_bf16_fast(e_)       \
                                         : (short)0;                         \
    }

#define GAT_PA(PAH0, PAH1, SM_, Q0, Q1, Q2, Q3)                              \
    {                                                                        \
        GAT_ELEM(PAH0, 0, (SM_) + ra0[0], Q0, 0)                             \
        GAT_ELEM(PAH0, 1, (SM_) + ra0[1], Q1, 0)                             \
        GAT_ELEM(PAH0, 2, (SM_) + ra0[2], Q2, 0)                             \
        GAT_ELEM(PAH0, 3, (SM_) + ra0[3], Q3, 0)                             \
        GAT_ELEM(PAH0, 4, (SM_) + ra1[0], Q0, 1)                             \
        GAT_ELEM(PAH0, 5, (SM_) + ra1[1], Q1, 1)                             \
        GAT_ELEM(PAH0, 6, (SM_) + ra1[2], Q2, 1)                             \
        GAT_ELEM(PAH0, 7, (SM_) + ra1[3], Q3, 1)                             \
        GAT_ELEM(PAH1, 0, (SM_) + rb0[0], Q0, 8)                             \
        GAT_ELEM(PAH1, 1, (SM_) + rb0[1], Q1, 8)                             \
        GAT_ELEM(PAH1, 2, (SM_) + rb0[2], Q2, 8)                             \
        GAT_ELEM(PAH1, 3, (SM_) + rb0[3], Q3, 8)                             \
        GAT_ELEM(PAH1, 4, (SM_) + rb1[0], Q0, 9)                             \
        GAT_ELEM(PAH1, 5, (SM_) + rb1[1], Q1, 9)                             \
        GAT_ELEM(PAH1, 6, (SM_) + rb1[2], Q2, 9)                             \
        GAT_ELEM(PAH1, 7, (SM_) + rb1[3], Q3, 9)                             \
    }

#define GAT_MFMA_HALF(H_)                                                    \
    {                                                                        \
        const short* bp_ = Gfrag + ((size_t)ktg * 8 + (H_) * 4) * 512 +      \
                           lane * 8;                                         \
        short8 bv0 = *(const short8*)(bp_);                                  \
        short8 bv1 = *(const short8*)(bp_ + 512);                            \
        short8 bv2 = *(const short8*)(bp_ + 1024);                           \
        short8 bv3 = *(const short8*)(bp_ + 1536);                           \
        acc[0][0] = __builtin_amdgcn_mfma_f32_16x16x32_bf16(pa0[H_], bv0,    \
                                                            acc[0][0], 0, 0, 0); \
        acc[0][1] = __builtin_amdgcn_mfma_f32_16x16x32_bf16(pa0[H_], bv1,    \
                                                            acc[0][1], 0, 0, 0); \
        acc[0][2] = __builtin_amdgcn_mfma_f32_16x16x32_bf16(pa0[H_], bv2,    \
                                                            acc[0][2], 0, 0, 0); \
        acc[0][3] = __builtin_amdgcn_mfma_f32_16x16x32_bf16(pa0[H_], bv3,    \
                                                            acc[0][3], 0, 0, 0); \
        acc[0][4] = __builtin_amdgcn_mfma_f32_16x16x32_bf16(pa0[H_], onesB,  \
                                                            acc[0][4], 0, 0, 0); \
        acc[1][0] = __builtin_amdgcn_mfma_f32_16x16x32_bf16(pa1[H_], bv0,    \
                                                            acc[1][0], 0, 0, 0); \
        acc[1][1] = __builtin_amdgcn_mfma_f32_16x16x32_bf16(pa1[H_], bv1,    \
                                                            acc[1][1], 0, 0, 0); \
        acc[1][2] = __builtin_amdgcn_mfma_f32_16x16x32_bf16(pa1[H_], bv2,    \
                                                            acc[1][2], 0, 0, 0); \
        acc[1][3] = __builtin_amdgcn_mfma_f32_16x16x32_bf16(pa1[H_], bv3,    \
                                                            acc[1][3], 0, 0, 0); \
        acc[1][4] = __builtin_amdgcn_mfma_f32_16x16x32_bf16(pa1[H_], onesB,  \
                                                            acc[1][4], 0, 0, 0); \
    }

__global__ __launch_bounds__(256, 3) void gat_pv8(
    const int* __restrict__ A, const short* __restrict__ Gfrag,
    const float* __restrict__ sV, const float* __restrict__ rV,
    float* __restrict__ accP, float* __restrict__ denP) {
    __shared__ float Ls[4][32][68];
    __shared__ float Ld[4][32];

    const int tid = threadIdx.x;
    const int wave = tid >> 6, lane = tid & 63;
    const int l15 = lane & 15, lhi = lane >> 4;
    const int rb = blockIdx.x / 3;
    const int ks3 = blockIdx.x - rb * 3;
    const int i0 = rb * 32;
    const int tstart = ks3 * 43;
    const int tcnt = (ks3 < 2) ? 43 : 42;

    const int r3 = l15 & 3;
    const int shBase = ((l15 >> 2) << 4) + (lhi << 1);

    const float s0m = sV[i0 + l15];
    const float s1m = sV[i0 + 16 + l15];
    const int* ab0 = A + (size_t)(i0 + lhi * 4) * NN + l15 * 4;
    const int* ab1 = ab0 + (size_t)16 * NN;
    const float* rvb = rV + lhi * 8;

    short8 onesB;
#pragma unroll
    for (int j = 0; j < 8; j++) onesB[j] = (l15 == 0) ? (short)0x3F80 : (short)0;

    f32x4 acc[2][5];
#pragma unroll
    for (int rg = 0; rg < 2; rg++)
#pragma unroll
        for (int n = 0; n < 5; n++) acc[rg][n] = (f32x4){0.f, 0.f, 0.f, 0.f};

    i32x4 s00, s01, s02, s03, s10, s11, s12, s13;
    GAT_LOADA(s00, s01, s02, s03, ab0, tstart + wave);
    GAT_LOADA(s10, s11, s12, s13, ab1, tstart + wave);

    for (int tt = wave; tt < tcnt; tt += 4) {
        const int ktg = tstart + tt;
        const int k0 = ktg * 64;
        f32x4 ra0 = *(const f32x4*)(rvb + k0);
        f32x4 ra1 = *(const f32x4*)(rvb + k0 + 4);
        f32x4 rb0 = *(const f32x4*)(rvb + k0 + 32);
        f32x4 rb1 = *(const f32x4*)(rvb + k0 + 36);

        unsigned int q00, q01, q02, q03, q10, q11, q12, q13;
        GAT_BAL(q00, q01, q02, q03, s00, s01, s02, s03);
        GAT_BAL(q10, q11, q12, q13, s10, s11, s12, s13);

        const int tn = (tt + 4 < tcnt) ? ktg + 4 : ktg;  // tail: redundant reload
        GAT_LOADA(s00, s01, s02, s03, ab0, tn);
        GAT_LOADA(s10, s11, s12, s13, ab1, tn);

        short8 pa0[2], pa1[2];
        GAT_PA(pa0[0], pa0[1], s0m, q00, q01, q02, q03);
        GAT_PA(pa1[0], pa1[1], s1m, q10, q11, q12, q13);

        GAT_MFMA_HALF(0);
        GAT_MFMA_HALF(1);
    }

    // combine the 4 waves' partials in LDS (single barrier, no atomics)
#pragma unroll
    for (int rg = 0; rg < 2; rg++)
#pragma unroll
        for (int n = 0; n < 4; n++)
#pragma unroll
            for (int q = 0; q < 4; q++)
                Ls[wave][rg * 16 + lhi * 4 + q][n * 16 + l15] = acc[rg][n][q];
    if (l15 == 0) {
#pragma unroll
        for (int rg = 0; rg < 2; rg++)
#pragma unroll
            for (int q = 0; q < 4; q++)
                Ld[wave][rg * 16 + lhi * 4 + q] = acc[rg][4][q];
    }
    __syncthreads();

    const int row = tid >> 3, c0 = (tid & 7) * 8;
    float v[8];
#pragma unroll
    for (int j = 0; j < 8; j++)
        v[j] = Ls[0][row][c0 + j] + Ls[1][row][c0 + j] +
               Ls[2][row][c0 + j] + Ls[3][row][c0 + j];
    float* aout = accP + (size_t)ks3 * NN * 64 + (size_t)(i0 + row) * 64 + c0;
    *(f32x4*)aout = (f32x4){v[0], v[1], v[2], v[3]};
    *((f32x4*)aout + 1) = (f32x4){v[4], v[5], v[6], v[7]};
    if (tid < 32)
        denP[(size_t)ks3 * NN + i0 + tid] =
            Ld[0][tid] + Ld[1][tid] + Ld[2][tid] + Ld[3][tid];
}

// ---------------- kernel 4: sum 3 partials, divide, cast --------------------
__global__ void gat_final(const float* __restrict__ accP, const float* __restrict__ denP,
                          const int* __restrict__ flag, void* __restrict__ outP) {
    int idx = blockIdx.x * blockDim.x + threadIdx.x;  // one f32x4 group
    if (idx >= NN * 16) return;
    int row = idx >> 4;
    float den = 0.f;
    f32x4 v = (f32x4){0.f, 0.f, 0.f, 0.f};
#pragma unroll
    for (int sk = 0; sk < 3; sk++) {
        den += denP[(size_t)sk * NN + row];
        f32x4 a = *((const f32x4*)(accP + (size_t)sk * NN * 64) + idx);
        v.x += a.x; v.y += a.y; v.z += a.z; v.w += a.w;
    }
    float inv = 1.0f / den;
    v.x *= inv; v.y *= inv; v.z *= inv; v.w *= inv;
    if (*flag) {
        short4v pk;
#pragma unroll
        for (int j = 0; j < 4; j++) pk[j] = (short)f32_to_bf16(v[j]);
        *((short4v*)outP + idx) = pk;
    } else {
        *((f32x4*)outP + idx) = v;
    }
}

// ---------------- launch -----------------------------------------------------
extern "C" void kernel_launch(void* const* d_in, const int* in_sizes, int n_in,
                              void* d_out, int out_size, void* d_ws, size_t ws_size,
                              hipStream_t stream) {
    const void* X  = d_in[0];
    const int*  A  = (const int*)d_in[1];
    const void* W  = d_in[2];
    const void* bb = d_in[3];
    const void* as_ = d_in[4];
    const void* ar_ = d_in[5];

    char* ws = (char*)d_ws;
    const size_t OFF_FLAG = 0;
    const size_t OFF_XB   = 256;
    const size_t OFF_WB   = OFF_XB + (size_t)NN * 256 * 2;
    const size_t OFF_BF   = OFF_WB + (size_t)256 * 256 * 2;
    const size_t OFF_ASF  = OFF_BF + 1024;
    const size_t OFF_ARF  = OFF_ASF + 1024;
    const size_t OFF_S    = OFF_ARF + 1024;
    const size_t OFF_R    = OFF_S + (size_t)NN * 4;
    const size_t OFF_GF   = OFF_R + (size_t)NN * 4;           // Gfrag, 1 MB
    const size_t OFF_ACC  = OFF_GF + (size_t)64 * NN * 2;
    const size_t OFF_DEN  = OFF_ACC + (size_t)3 * NN * 64 * 4;

    int*   flag = (int*)(ws + OFF_FLAG);
    short* Xb   = (short*)(ws + OFF_XB);
    short* Wb   = (short*)(ws + OFF_WB);
    float* bF   = (float*)(ws + OFF_BF);
    float* asF  = (float*)(ws + OFF_ASF);
    float* arF  = (float*)(ws + OFF_ARF);
    float* sP   = (float*)(ws + OFF_S);
    float* rP   = (float*)(ws + OFF_R);
    short* Gf   = (short*)(ws + OFF_GF);
    float* accP = (float*)(ws + OFF_ACC);
    float* denP = (float*)(ws + OFF_DEN);

    gat_prep<<<256, 256, 0, stream>>>(X, W, bb, as_, ar_, Xb, Wb, bF, asF, arF, flag);
    gat_gemm1<<<NN / 32, 128, 0, stream>>>(Xb, Wb, bF, asF, arF, Gf, sP, rP);
    gat_pv8<<<256 * 3, 256, 0, stream>>>(A, Gf, sP, rP, accP, denP);
    gat_final<<<NN * 16 / 256, 256, 0, stream>>>(accP, denP, flag, d_out);
}